// Round 4
// baseline (233.775 us; speedup 1.0000x reference)
//
#include <hip/hip_runtime.h>
#include <hip/hip_bf16.h>

#define ALPHA_C 0.9f
#define EPS_C 1e-3f

typedef unsigned short u16;
typedef __attribute__((ext_vector_type(8))) short short8;
typedef __attribute__((ext_vector_type(4))) float f32x4;
#define MFMA(a, b, c) __builtin_amdgcn_mfma_f32_16x16x32_bf16(a, b, c, 0, 0, 0)

__device__ __forceinline__ u16 f2bf(float f) {
  union { float f; unsigned u; } v; v.f = f;
  unsigned u = v.u;
  u += 0x7FFFu + ((u >> 16) & 1u);
  return (u16)(u >> 16);
}
__device__ __forceinline__ float bf2f(u16 h) {
  union { unsigned u; float f; } v; v.u = ((unsigned)h) << 16;
  return v.f;
}
__device__ __forceinline__ unsigned pkbf(float a, float b) {
  __hip_bfloat162 t = __float22bfloat162_rn(float2{a, b});
  union { __hip_bfloat162 h; unsigned u; } cv; cv.h = t; return cv.u;
}

// ---------------------------------------------------------------------------
// K0: weight conversion fp32 -> bf16 (natural + transposed copies)
__global__ __launch_bounds__(256) void k_conv(
    const float* __restrict__ W1, const float* __restrict__ W2, const float* __restrict__ W3,
    const float* __restrict__ V1, const float* __restrict__ V2,
    u16* __restrict__ W1T, u16* __restrict__ W1n, u16* __restrict__ W2T, u16* __restrict__ W2n,
    u16* __restrict__ W3T, u16* __restrict__ W3n, u16* __restrict__ V1T, u16* __restrict__ V1n,
    u16* __restrict__ V2T, u16* __restrict__ V2n) {
  int i = blockIdx.x * 256 + threadIdx.x;   // 0..32767
  { float v = W1[i]; int k = i >> 6, j = i & 63; u16 b = f2bf(v); W1n[i] = b; W1T[j * 512 + k] = b; }
  { float v = V1[i]; int k = i >> 6, j = i & 63; u16 b = f2bf(v); V1n[i] = b; V1T[j * 512 + k] = b; }
  { float v = W3[i]; int k = i >> 9, n = i & 511; u16 b = f2bf(v); W3n[i] = b; W3T[n * 64 + k] = b; }
  if (i < 4096) {
    { float v = W2[i]; int k = i >> 6, j = i & 63; u16 b = f2bf(v); W2n[i] = b; W2T[j * 64 + k] = b; }
    { float v = V2[i]; int k = i >> 6, j = i & 63; u16 b = f2bf(v); V2n[i] = b; V2T[j * 64 + k] = b; }
  }
}

// ---------------------------------------------------------------------------
// K1 (fused fwd): H1=relu(xW1+b1); H2=relu(H1W2+b2); F=H2W3+b3 -> Fb bf16;
//  G1=relu(FV1+c1); g2pre=G1V2+c2; s3=mask2*V3; s2=(s3 V2^T)*mask1 -> S2b;
//  lyap = sum(relu(g2pre)*V3)+c3+eps*||F||^2 -> LYAP. Also H1b,H2b masks.
// LDS: As 17408 + Bs 18432 + Cs 9216 = 45056 B -> 3 blocks/CU
__global__ __launch_bounds__(256) void k_fwd(
    const float* __restrict__ x,
    const u16* __restrict__ W1T, const float* __restrict__ b1,
    const u16* __restrict__ W2T, const float* __restrict__ b2,
    const u16* __restrict__ W3T, const float* __restrict__ b3,
    const u16* __restrict__ V1T, const float* __restrict__ c1,
    const u16* __restrict__ V2Tb, const u16* __restrict__ V2nb, const float* __restrict__ c2,
    const float* __restrict__ V3, const float* __restrict__ c3,
    u16* __restrict__ H1b, u16* __restrict__ H2b,
    u16* __restrict__ Fb, u16* __restrict__ S2b, float* __restrict__ LYAP) {
  __shared__ u16 As[64 * 136];   // x chunk / F chunk
  __shared__ u16 Bs[128 * 72];   // weight chunks; also viewed [64][136]
  __shared__ u16 Cs[64 * 72];    // H1 / H2 / G1 / s3
  const int tid = threadIdx.x;
  const int lane = tid & 63, w = tid >> 6, q = lane >> 4, r = lane & 15;
  const int m0 = blockIdx.x * 64;

  // ---- stage 1: H1 = relu(x W1 + b1)
  f32x4 acc[4] = {};
  for (int kc = 0; kc < 4; ++kc) {
    __syncthreads();
    #pragma unroll
    for (int c = 0; c < 8; ++c) {
      int idx = c * 256 + tid; int rr = idx >> 5, k4 = (idx & 31) * 4;
      float4 v = *(const float4*)&x[(size_t)(m0 + rr) * 512 + kc * 128 + k4];
      uint2 pv; pv.x = pkbf(v.x, v.y); pv.y = pkbf(v.z, v.w);
      *(uint2*)&As[rr * 136 + k4] = pv;
    }
    #pragma unroll
    for (int c = 0; c < 4; ++c) {
      int idx = c * 256 + tid; int rr = idx >> 4, k8 = (idx & 15) * 8;
      *(short8*)&Bs[rr * 136 + k8] = *(const short8*)&W1T[rr * 512 + kc * 128 + k8];
    }
    __syncthreads();
    #pragma unroll
    for (int ks = 0; ks < 4; ++ks) {
      short8 a = *(const short8*)&As[(w * 16 + r) * 136 + ks * 32 + q * 8];
      #pragma unroll
      for (int t = 0; t < 4; ++t) {
        short8 b = *(const short8*)&Bs[(t * 16 + r) * 136 + ks * 32 + q * 8];
        acc[t] = MFMA(a, b, acc[t]);
      }
    }
  }
  // H1 -> Cs (own rows)
  #pragma unroll
  for (int t = 0; t < 4; ++t) {
    int col = t * 16 + r; float bv = b1[col];
    #pragma unroll
    for (int g = 0; g < 4; ++g) {
      float h = acc[t][g] + bv; h = h > 0.f ? h : 0.f;
      Cs[(w * 16 + q * 4 + g) * 72 + col] = f2bf(h);
    }
  }
  __syncthreads();
  // W2T -> Bs[0..]; store H1b from Cs
  #pragma unroll
  for (int c = 0; c < 2; ++c) {
    int idx = c * 256 + tid; int a = idx >> 3, k8 = (idx & 7) * 8;
    *(short8*)&Bs[a * 72 + k8] = *(const short8*)&W2T[a * 64 + k8];
    *(short8*)&H1b[(size_t)(m0 + a) * 64 + k8] = *(const short8*)&Cs[a * 72 + k8];
  }
  __syncthreads();
  // ---- stage 2: H2 = relu(H1 W2 + b2)
  f32x4 acc2[4] = {};
  #pragma unroll
  for (int ks = 0; ks < 2; ++ks) {
    short8 a = *(const short8*)&Cs[(w * 16 + r) * 72 + ks * 32 + q * 8];
    #pragma unroll
    for (int t = 0; t < 4; ++t) {
      short8 b = *(const short8*)&Bs[(t * 16 + r) * 72 + ks * 32 + q * 8];
      acc2[t] = MFMA(a, b, acc2[t]);
    }
  }
  #pragma unroll
  for (int t = 0; t < 4; ++t) {
    int col = t * 16 + r; float bv = b2[col];
    #pragma unroll
    for (int g = 0; g < 4; ++g) {
      float h = acc2[t][g] + bv; h = h > 0.f ? h : 0.f;
      Cs[(w * 16 + q * 4 + g) * 72 + col] = f2bf(h);   // own rows, own MFMA consumed H1 already
    }
  }
  __syncthreads();
  #pragma unroll
  for (int c = 0; c < 2; ++c) {
    int idx = c * 256 + tid; int a = idx >> 3, k8 = (idx & 7) * 8;
    *(short8*)&H2b[(size_t)(m0 + a) * 64 + k8] = *(const short8*)&Cs[a * 72 + k8];
  }
  // ---- stage 3: F = H2 W3 + b3 ; G1 accumulation
  f32x4 g1acc[4] = {};
  float ssq[4] = {0.f, 0.f, 0.f, 0.f};
  for (int nc = 0; nc < 4; ++nc) {
    __syncthreads();
    #pragma unroll
    for (int c = 0; c < 4; ++c) {
      int idx = c * 256 + tid; int nl = idx >> 3, k8 = (idx & 7) * 8;
      *(short8*)&Bs[nl * 72 + k8] = *(const short8*)&W3T[(size_t)(nc * 128 + nl) * 64 + k8];
    }
    __syncthreads();
    f32x4 facc[8] = {};
    #pragma unroll
    for (int ks = 0; ks < 2; ++ks) {
      short8 a = *(const short8*)&Cs[(w * 16 + r) * 72 + ks * 32 + q * 8];
      #pragma unroll
      for (int t = 0; t < 8; ++t) {
        short8 b = *(const short8*)&Bs[(t * 16 + r) * 72 + ks * 32 + q * 8];
        facc[t] = MFMA(a, b, facc[t]);
      }
    }
    #pragma unroll
    for (int t = 0; t < 8; ++t) {
      int colg = nc * 128 + t * 16 + r;
      float bv = b3[colg];
      #pragma unroll
      for (int g = 0; g < 4; ++g) {
        float v = facc[t][g] + bv;
        ssq[g] += v * v;
        As[(w * 16 + q * 4 + g) * 136 + t * 16 + r] = f2bf(v);
      }
    }
    __syncthreads();
    #pragma unroll
    for (int c = 0; c < 4; ++c) {
      int idx = c * 256 + tid; int jj = idx >> 4, k8 = (idx & 15) * 8;
      *(short8*)&Bs[jj * 136 + k8] = *(const short8*)&V1T[(size_t)jj * 512 + nc * 128 + k8];
    }
    __syncthreads();
    #pragma unroll
    for (int ks = 0; ks < 4; ++ks) {
      short8 a = *(const short8*)&As[(w * 16 + r) * 136 + ks * 32 + q * 8];
      #pragma unroll
      for (int t = 0; t < 4; ++t) {
        short8 b = *(const short8*)&Bs[(t * 16 + r) * 136 + ks * 32 + q * 8];
        g1acc[t] = MFMA(a, b, g1acc[t]);
      }
    }
    #pragma unroll
    for (int c = 0; c < 4; ++c) {
      int idx = c * 256 + tid; int rr = idx >> 4, k8 = (idx & 15) * 8;
      *(short8*)&Fb[(size_t)(m0 + rr) * 512 + nc * 128 + k8] = *(const short8*)&As[rr * 136 + k8];
    }
  }
  __syncthreads();   // all facc reads of Cs done
  // ---- stage 4: G1 -> Cs ; g2 ; s3 ; s2
  f32x4 g1v[4];
  #pragma unroll
  for (int t = 0; t < 4; ++t) {
    int col = t * 16 + r; float cv = c1[col];
    #pragma unroll
    for (int g = 0; g < 4; ++g) {
      float v = g1acc[t][g] + cv; v = v > 0.f ? v : 0.f;
      g1v[t][g] = v;
      Cs[(w * 16 + q * 4 + g) * 72 + col] = f2bf(v);
    }
  }
  #pragma unroll
  for (int c = 0; c < 2; ++c) {
    int idx = c * 256 + tid; int a = idx >> 3, k8 = (idx & 7) * 8;
    *(short8*)&Bs[a * 72 + k8] = *(const short8*)&V2Tb[a * 64 + k8];
  }
  __syncthreads();
  f32x4 g2acc[4] = {};
  #pragma unroll
  for (int ks = 0; ks < 2; ++ks) {
    short8 a = *(const short8*)&Cs[(w * 16 + r) * 72 + ks * 32 + q * 8];
    #pragma unroll
    for (int t = 0; t < 4; ++t) {
      short8 b = *(const short8*)&Bs[(t * 16 + r) * 72 + ks * 32 + q * 8];
      g2acc[t] = MFMA(a, b, g2acc[t]);
    }
  }
  __syncthreads();
  float tot[4] = {0.f, 0.f, 0.f, 0.f};
  #pragma unroll
  for (int t = 0; t < 4; ++t) {
    int col = t * 16 + r;
    float c2v = c2[col], v3v = V3[col];
    #pragma unroll
    for (int g = 0; g < 4; ++g) {
      float pre = g2acc[t][g] + c2v;
      float g2 = pre > 0.f ? pre : 0.f;
      float s3 = pre > 0.f ? v3v : 0.f;
      Cs[(w * 16 + q * 4 + g) * 72 + col] = f2bf(s3);
      tot[g] += g2 * v3v;
    }
  }
  #pragma unroll
  for (int c = 0; c < 2; ++c) {
    int idx = c * 256 + tid; int a = idx >> 3, k8 = (idx & 7) * 8;
    *(short8*)&Bs[a * 72 + k8] = *(const short8*)&V2nb[a * 64 + k8];
  }
  __syncthreads();
  f32x4 s2acc[4] = {};
  #pragma unroll
  for (int ks = 0; ks < 2; ++ks) {
    short8 a = *(const short8*)&Cs[(w * 16 + r) * 72 + ks * 32 + q * 8];
    #pragma unroll
    for (int t = 0; t < 4; ++t) {
      short8 b = *(const short8*)&Bs[(t * 16 + r) * 72 + ks * 32 + q * 8];
      s2acc[t] = MFMA(a, b, s2acc[t]);
    }
  }
  #pragma unroll
  for (int t = 0; t < 4; ++t) {
    int col = t * 16 + r;
    #pragma unroll
    for (int g = 0; g < 4; ++g) {
      float sv = g1v[t][g] > 0.f ? s2acc[t][g] : 0.f;
      S2b[(size_t)(m0 + w * 16 + q * 4 + g) * 64 + col] = f2bf(sv);
    }
  }
  float c3v = c3[0];
  #pragma unroll
  for (int g = 0; g < 4; ++g) {
    float s = tot[g] + EPS_C * ssq[g];
    s += __shfl_xor(s, 1); s += __shfl_xor(s, 2); s += __shfl_xor(s, 4); s += __shfl_xor(s, 8);
    if (r == 0) LYAP[m0 + w * 16 + q * 4 + g] = s + c3v;
  }
}

// ---------------------------------------------------------------------------
// K2: U = s2 V1^T + 2eps*F ; T3 = (U W3^T)*(H2>0) ; T2 = (T3 W2^T)*(H1>0) -> T2b;
//     GV = T2 W1^T (regs), dot; NUM = relu(dot+a*lyap); denom -> DP[0]
// LDS 45 KB -> 3 blocks/CU
__global__ __launch_bounds__(256) void k_utg(
    const u16* __restrict__ S2b, const u16* __restrict__ V1n, const u16* __restrict__ Fb,
    const u16* __restrict__ W3n, const u16* __restrict__ W2n, const u16* __restrict__ W1n,
    const u16* __restrict__ H1b, const u16* __restrict__ H2b,
    const float* __restrict__ LYAP,
    u16* __restrict__ T2b, float* __restrict__ NUM, float* __restrict__ DP) {
  __shared__ u16 As[64 * 136];   // F chunk -> U chunk
  __shared__ u16 Bs[128 * 72];   // weight chunks; [64][136] view
  __shared__ u16 Cs[64 * 72];    // S2 -> T3 -> T2
  const int tid = threadIdx.x;
  const int lane = tid & 63, w = tid >> 6, q = lane >> 4, r = lane & 15;
  const int m0 = blockIdx.x * 64;

  #pragma unroll
  for (int c = 0; c < 2; ++c) {
    int idx = c * 256 + tid; int a = idx >> 3, k8 = (idx & 7) * 8;
    *(short8*)&Cs[a * 72 + k8] = *(const short8*)&S2b[(size_t)(m0 + a) * 64 + k8];
  }
  f32x4 t3acc[4] = {};
  for (int nc = 0; nc < 4; ++nc) {
    __syncthreads();
    #pragma unroll
    for (int c = 0; c < 4; ++c) {
      int idx = c * 256 + tid; int rr = idx >> 4, k8 = (idx & 15) * 8;
      *(short8*)&As[rr * 136 + k8] = *(const short8*)&Fb[(size_t)(m0 + rr) * 512 + nc * 128 + k8];
    }
    #pragma unroll
    for (int c = 0; c < 4; ++c) {
      int idx = c * 256 + tid; int nl = idx >> 3, k8 = (idx & 7) * 8;
      *(short8*)&Bs[nl * 72 + k8] = *(const short8*)&V1n[(size_t)(nc * 128 + nl) * 64 + k8];
    }
    __syncthreads();
    f32x4 uacc[8] = {};
    #pragma unroll
    for (int ks = 0; ks < 2; ++ks) {
      short8 a = *(const short8*)&Cs[(w * 16 + r) * 72 + ks * 32 + q * 8];
      #pragma unroll
      for (int t = 0; t < 8; ++t) {
        short8 b = *(const short8*)&Bs[(t * 16 + r) * 72 + ks * 32 + q * 8];
        uacc[t] = MFMA(a, b, uacc[t]);
      }
    }
    #pragma unroll
    for (int t = 0; t < 8; ++t) {
      #pragma unroll
      for (int g = 0; g < 4; ++g) {
        int addr = (w * 16 + q * 4 + g) * 136 + t * 16 + r;
        As[addr] = f2bf(uacc[t][g] + 2.f * EPS_C * bf2f(As[addr]));
      }
    }
    __syncthreads();
    #pragma unroll
    for (int c = 0; c < 4; ++c) {
      int idx = c * 256 + tid; int jj = idx >> 4, k8 = (idx & 15) * 8;
      *(short8*)&Bs[jj * 136 + k8] = *(const short8*)&W3n[(size_t)jj * 512 + nc * 128 + k8];
    }
    __syncthreads();
    #pragma unroll
    for (int ks = 0; ks < 4; ++ks) {
      short8 a = *(const short8*)&As[(w * 16 + r) * 136 + ks * 32 + q * 8];
      #pragma unroll
      for (int t = 0; t < 4; ++t) {
        short8 b = *(const short8*)&Bs[(t * 16 + r) * 136 + ks * 32 + q * 8];
        t3acc[t] = MFMA(a, b, t3acc[t]);
      }
    }
  }
  __syncthreads();
  // W2n -> Bs ; T3 (masked) -> Cs own rows
  #pragma unroll
  for (int c = 0; c < 2; ++c) {
    int idx = c * 256 + tid; int a = idx >> 3, k8 = (idx & 7) * 8;
    *(short8*)&Bs[a * 72 + k8] = *(const short8*)&W2n[a * 64 + k8];
  }
  #pragma unroll
  for (int t = 0; t < 4; ++t) {
    int col = t * 16 + r;
    #pragma unroll
    for (int g = 0; g < 4; ++g) {
      int rl = w * 16 + q * 4 + g;
      u16 h2u = H2b[(size_t)(m0 + rl) * 64 + col];
      Cs[rl * 72 + col] = h2u ? f2bf(t3acc[t][g]) : 0;
    }
  }
  __syncthreads();
  f32x4 t2acc[4] = {};
  #pragma unroll
  for (int ks = 0; ks < 2; ++ks) {
    short8 a = *(const short8*)&Cs[(w * 16 + r) * 72 + ks * 32 + q * 8];
    #pragma unroll
    for (int t = 0; t < 4; ++t) {
      short8 b = *(const short8*)&Bs[(t * 16 + r) * 72 + ks * 32 + q * 8];
      t2acc[t] = MFMA(a, b, t2acc[t]);
    }
  }
  // T2 (masked) -> T2b + Cs own rows (own MFMA consumed T3 already)
  #pragma unroll
  for (int t = 0; t < 4; ++t) {
    int col = t * 16 + r;
    #pragma unroll
    for (int g = 0; g < 4; ++g) {
      int rl = w * 16 + q * 4 + g;
      u16 h1u = H1b[(size_t)(m0 + rl) * 64 + col];
      u16 tv = h1u ? f2bf(t2acc[t][g]) : 0;
      T2b[(size_t)(m0 + rl) * 64 + col] = tv;
      Cs[rl * 72 + col] = tv;
    }
  }
  // GV stage: ssq = row-wise ||T2 W1^T||^2
  float ssq[4] = {0.f, 0.f, 0.f, 0.f};
  for (int nc = 0; nc < 4; ++nc) {
    __syncthreads();
    #pragma unroll
    for (int c = 0; c < 4; ++c) {
      int idx = c * 256 + tid; int nl = idx >> 3, k8 = (idx & 7) * 8;
      *(short8*)&Bs[nl * 72 + k8] = *(const short8*)&W1n[(size_t)(nc * 128 + nl) * 64 + k8];
    }
    __syncthreads();
    f32x4 acc[8] = {};
    #pragma unroll
    for (int ks = 0; ks < 2; ++ks) {
      short8 a = *(const short8*)&Cs[(w * 16 + r) * 72 + ks * 32 + q * 8];
      #pragma unroll
      for (int t = 0; t < 8; ++t) {
        short8 b = *(const short8*)&Bs[(t * 16 + r) * 72 + ks * 32 + q * 8];
        acc[t] = MFMA(a, b, acc[t]);
      }
    }
    #pragma unroll
    for (int t = 0; t < 8; ++t)
      #pragma unroll
      for (int g = 0; g < 4; ++g) ssq[g] += acc[t][g] * acc[t][g];
  }
  float totw = 0.f;
  #pragma unroll
  for (int g = 0; g < 4; ++g) {
    float s = ssq[g];
    s += __shfl_xor(s, 1); s += __shfl_xor(s, 2); s += __shfl_xor(s, 4); s += __shfl_xor(s, 8);
    if (r == 0) {
      int rowg = m0 + w * 16 + q * 4 + g;
      float nm = s + ALPHA_C * LYAP[rowg];
      NUM[rowg] = nm > 0.f ? nm : 0.f;
    }
    s += __shfl_xor(s, 16); s += __shfl_xor(s, 32);
    totw += s;
  }
  if (lane == 0) atomicAdd(&DP[0], totw);
}

// ---------------------------------------------------------------------------
// K3: recompute GV from T2; out = F - (NUM/DP[0])*GV
__global__ __launch_bounds__(256) void k_out(
    const u16* __restrict__ T2b, const u16* __restrict__ W1n,
    const u16* __restrict__ Fb, const float* __restrict__ NUM, const float* __restrict__ DP,
    float* __restrict__ out) {
  __shared__ u16 As[64 * 136];
  __shared__ u16 Bs[128 * 72];
  __shared__ u16 Cs[64 * 72];
  const int tid = threadIdx.x;
  const int lane = tid & 63, w = tid >> 6, q = lane >> 4, r = lane & 15;
  const int m0 = blockIdx.x * 64;
  #pragma unroll
  for (int c = 0; c < 2; ++c) {
    int idx = c * 256 + tid; int a = idx >> 3, k8 = (idx & 7) * 8;
    *(short8*)&Cs[a * 72 + k8] = *(const short8*)&T2b[(size_t)(m0 + a) * 64 + k8];
  }
  const float inv_denom = 1.f / DP[0];
  float sc[4];
  #pragma unroll
  for (int g = 0; g < 4; ++g) sc[g] = NUM[m0 + w * 16 + q * 4 + g] * inv_denom;
  for (int nc = 0; nc < 4; ++nc) {
    __syncthreads();
    #pragma unroll
    for (int c = 0; c < 4; ++c) {
      int idx = c * 256 + tid; int nl = idx >> 3, k8 = (idx & 7) * 8;
      *(short8*)&Bs[nl * 72 + k8] = *(const short8*)&W1n[(size_t)(nc * 128 + nl) * 64 + k8];
    }
    #pragma unroll
    for (int c = 0; c < 4; ++c) {
      int idx = c * 256 + tid; int rr = idx >> 4, k8 = (idx & 15) * 8;
      *(short8*)&As[rr * 136 + k8] = *(const short8*)&Fb[(size_t)(m0 + rr) * 512 + nc * 128 + k8];
    }
    __syncthreads();
    f32x4 acc[8] = {};
    #pragma unroll
    for (int ks = 0; ks < 2; ++ks) {
      short8 a = *(const short8*)&Cs[(w * 16 + r) * 72 + ks * 32 + q * 8];
      #pragma unroll
      for (int t = 0; t < 8; ++t) {
        short8 b = *(const short8*)&Bs[(t * 16 + r) * 72 + ks * 32 + q * 8];
        acc[t] = MFMA(a, b, acc[t]);
      }
    }
    #pragma unroll
    for (int t = 0; t < 8; ++t) {
      int colg = nc * 128 + t * 16 + r;
      #pragma unroll
      for (int g = 0; g < 4; ++g) {
        int rl = w * 16 + q * 4 + g;
        float fv = bf2f(As[rl * 136 + t * 16 + r]);
        out[(size_t)(m0 + rl) * 512 + colg] = fv - sc[g] * acc[t][g];
      }
    }
  }
}

// ---------------------------------------------------------------------------
extern "C" void kernel_launch(void* const* d_in, const int* in_sizes, int n_in,
                              void* d_out, int out_size, void* d_ws, size_t ws_size,
                              hipStream_t stream) {
  const float* x  = (const float*)d_in[0];
  const float* W1 = (const float*)d_in[1];
  const float* b1 = (const float*)d_in[2];
  const float* W2 = (const float*)d_in[3];
  const float* b2 = (const float*)d_in[4];
  const float* W3 = (const float*)d_in[5];
  const float* b3 = (const float*)d_in[6];
  const float* V1 = (const float*)d_in[7];
  const float* c1 = (const float*)d_in[8];
  const float* V2 = (const float*)d_in[9];
  const float* c2 = (const float*)d_in[10];
  const float* V3 = (const float*)d_in[11];
  const float* c3 = (const float*)d_in[12];
  float* out = (float*)d_out;

  u16* Fb = (u16*)d_ws;                       // 16777216 u16 = 32 MB
  float* LYAP = (float*)(Fb + 16777216);      // 32768 f
  float* NUM  = LYAP + 32768;
  float* DP   = NUM + 32768;                  // 256 f (only [0] used)
  u16* H1b  = (u16*)(DP + 256);
  u16* H2b  = H1b + 2097152;
  u16* S2b  = H2b + 2097152;
  u16* T2b  = S2b + 2097152;
  u16* W1Tb = T2b + 2097152;
  u16* W1nb = W1Tb + 32768;
  u16* W2Tb = W1nb + 32768;
  u16* W2nb = W2Tb + 4096;
  u16* W3Tb = W2nb + 4096;
  u16* W3nb = W3Tb + 32768;
  u16* V1Tb = W3nb + 32768;
  u16* V1nb = V1Tb + 32768;
  u16* V2Tb = V1nb + 32768;
  u16* V2nb = V2Tb + 4096;

  hipMemsetAsync(DP, 0, 256 * sizeof(float), stream);

  k_conv<<<128, 256, 0, stream>>>(W1, W2, W3, V1, V2,
                                  W1Tb, W1nb, W2Tb, W2nb, W3Tb, W3nb, V1Tb, V1nb, V2Tb, V2nb);
  k_fwd<<<512, 256, 0, stream>>>(x, W1Tb, b1, W2Tb, b2, W3Tb, b3, V1Tb, c1,
                                 V2Tb, V2nb, c2, V3, c3, H1b, H2b, Fb, S2b, LYAP);
  k_utg<<<512, 256, 0, stream>>>(S2b, V1nb, Fb, W3nb, W2nb, W1nb, H1b, H2b, LYAP, T2b, NUM, DP);
  k_out<<<512, 256, 0, stream>>>(T2b, W1nb, Fb, NUM, DP, out);
}